// Round 3
// baseline (107.426 us; speedup 1.0000x reference)
//
#include <hip/hip_runtime.h>
#include <math.h>

#define NTOK 4096
#define NDIM 1024
#define KTOT 2048
#define NEXP 64
#define NWAVE 8              // intra-block split-K waves
#define KCH  (KTOT / NWAVE)  // 256 k per wave
#define NSTEP (KCH / 32)     // 8 mfma K-steps per wave
#define RS   68              // LDS row stride (floats) for the reduce buffer

typedef _Float16 half8 __attribute__((ext_vector_type(8)));
typedef float    floatx4 __attribute__((ext_vector_type(4)));

#define XSCALE 16.0f
#define WSCALE 1024.0f
#define INVSCALE (1.0f / (16.0f * 1024.0f))

struct h2pair { _Float16 h, l; };
__device__ __forceinline__ h2pair split2(float v) {
    h2pair r;
    r.h = (_Float16)v;
    r.l = (_Float16)(v - (float)r.h);
    return r;
}

// ---------------------------------------------------------------------------
// gate_all: SINGLE fused kernel (prep_w eliminated).
//
// Evidence driving this version: the 2->4 waves/SIMD A/B was neutral (+1.2us,
// inside the +-1.5us noise band), and cycle arithmetic puts prep_w+gate_fused
// at ~8-10us combined; measured dur_us is dominated by the harness's 268MB
// workspace poison fill (44-46us @75% HBM peak, the only dispatches visible
// in rocprof top-5).  The one controllable cost left is the second kernel:
// its launch, its ~3us execution, and the WhT/WlT workspace round-trip.
//
// So: each wave converts its own W fragments fp32->fp16 hi/lo on the fly
// (W is 512KB, L2-resident; the 256x redundant re-read is ~4us of L2 traffic
// hidden under MFMA) and accumulates per-wave ||w_e||^2 partials, which join
// the existing split-K LDS reduction.  bh/bl bit patterns and the MFMA
// sequence are IDENTICAL to the two-kernel version; only the ||w||^2
// summation order changes (ulp-level).
//
// Block = 512 threads = 8 waves; wave w handles k-chunk [w*256,(w+1)*256)
// for the block's 16 tokens.  grid = NTOK/16 = 256 blocks.
// ---------------------------------------------------------------------------
__global__ __launch_bounds__(512) void gate_all(const float* __restrict__ t1,
                                                const float* __restrict__ t2,
                                                const float* __restrict__ W,
                                                float* __restrict__ out) {
    __shared__ float Sd[NWAVE][16 * RS];   // per-wave 16x64 partial dots (stride 68)
    __shared__ float Cn[NWAVE][16];        // per-wave per-token ||x||^2 partials
    __shared__ float Wn[NWAVE][NEXP];      // per-wave per-expert ||w||^2 partials

    const int tid  = threadIdx.x;
    const int lane = tid & 63;
    const int wv   = tid >> 6;            // 0..7 = split-K chunk
    const int tok0 = blockIdx.x * 16;
    const int kbase = wv * KCH;
    const int n  = lane & 15;             // fragment row (token / expert)
    const int fq = lane >> 4;             // k-octet selector

    // X: lane reads token tok0+n, k = kbase + step*32 + fq*8 .. +7
    const float* __restrict__ xb = ((kbase < NDIM)
        ? (t1 + (size_t)(tok0 + n) * NDIM + kbase)
        : (t2 + (size_t)(tok0 + n) * NDIM + (kbase - NDIM))) + fq * 8;
    // W: direct fp32, row 16j+n, k = kbase + s*32 + fq*8 .. +7 (L2-resident)
    const float* __restrict__ wb = W + kbase + fq * 8 + (size_t)n * KTOT;

    floatx4 acc[4];
    #pragma unroll
    for (int j = 0; j < 4; ++j) { acc[j][0]=0.f; acc[j][1]=0.f; acc[j][2]=0.f; acc[j][3]=0.f; }
    float ssx0 = 0.f, ssx1 = 0.f;         // dual accumulators: halve the fmaf dep chain
    float wss[4] = {0.f, 0.f, 0.f, 0.f};  // ||w_{16j+n}||^2 partials (this lane's octets)

    #pragma unroll
    for (int s = 0; s < NSTEP; ++s) {
        const float4 x0 = *reinterpret_cast<const float4*>(xb + s * 32);
        const float4 x1 = *reinterpret_cast<const float4*>(xb + s * 32 + 4);
        half8 bh[4], bl[4];
        #pragma unroll
        for (int j = 0; j < 4; ++j) {
            const float* wp = wb + (size_t)j * 16 * KTOT + s * 32;
            const float4 wa = *reinterpret_cast<const float4*>(wp);
            const float4 wc = *reinterpret_cast<const float4*>(wp + 4);
            wss[j] = fmaf(wa.x, wa.x, fmaf(wa.y, wa.y, fmaf(wa.z, wa.z, fmaf(wa.w, wa.w, wss[j]))));
            wss[j] = fmaf(wc.x, wc.x, fmaf(wc.y, wc.y, fmaf(wc.z, wc.z, fmaf(wc.w, wc.w, wss[j]))));
            const h2pair p0 = split2(wa.x * WSCALE), p1 = split2(wa.y * WSCALE);
            const h2pair p2 = split2(wa.z * WSCALE), p3 = split2(wa.w * WSCALE);
            const h2pair p4 = split2(wc.x * WSCALE), p5 = split2(wc.y * WSCALE);
            const h2pair p6 = split2(wc.z * WSCALE), p7 = split2(wc.w * WSCALE);
            bh[j][0]=p0.h; bh[j][1]=p1.h; bh[j][2]=p2.h; bh[j][3]=p3.h;
            bh[j][4]=p4.h; bh[j][5]=p5.h; bh[j][6]=p6.h; bh[j][7]=p7.h;
            bl[j][0]=p0.l; bl[j][1]=p1.l; bl[j][2]=p2.l; bl[j][3]=p3.l;
            bl[j][4]=p4.l; bl[j][5]=p5.l; bl[j][6]=p6.l; bl[j][7]=p7.l;
        }
        ssx0 = fmaf(x0.x, x0.x, fmaf(x0.y, x0.y, fmaf(x0.z, x0.z, fmaf(x0.w, x0.w, ssx0))));
        ssx1 = fmaf(x1.x, x1.x, fmaf(x1.y, x1.y, fmaf(x1.z, x1.z, fmaf(x1.w, x1.w, ssx1))));
        const h2pair q0 = split2(x0.x * XSCALE), q1 = split2(x0.y * XSCALE);
        const h2pair q2 = split2(x0.z * XSCALE), q3 = split2(x0.w * XSCALE);
        const h2pair q4 = split2(x1.x * XSCALE), q5 = split2(x1.y * XSCALE);
        const h2pair q6 = split2(x1.z * XSCALE), q7 = split2(x1.w * XSCALE);
        half8 ah, al;
        ah[0]=q0.h; ah[1]=q1.h; ah[2]=q2.h; ah[3]=q3.h; ah[4]=q4.h; ah[5]=q5.h; ah[6]=q6.h; ah[7]=q7.h;
        al[0]=q0.l; al[1]=q1.l; al[2]=q2.l; al[3]=q3.l; al[4]=q4.l; al[5]=q5.l; al[6]=q6.l; al[7]=q7.l;
        #pragma unroll
        for (int j = 0; j < 4; ++j)
            acc[j] = __builtin_amdgcn_mfma_f32_16x16x32_f16(ah, bh[j], acc[j], 0, 0, 0);
        #pragma unroll
        for (int j = 0; j < 4; ++j)
            acc[j] = __builtin_amdgcn_mfma_f32_16x16x32_f16(al, bh[j], acc[j], 0, 0, 0);
        #pragma unroll
        for (int j = 0; j < 4; ++j)
            acc[j] = __builtin_amdgcn_mfma_f32_16x16x32_f16(ah, bl[j], acc[j], 0, 0, 0);
    }

    // ---- deposit partial dots in LDS (C/D layout: token=fq*4+i, expert=16j+n)
    #pragma unroll
    for (int j = 0; j < 4; ++j) {
        #pragma unroll
        for (int i = 0; i < 4; ++i)
            Sd[wv][(fq * 4 + i) * RS + 16 * j + n] = acc[j][i];
    }
    // ---- token norm partials: combine the 4 fq-lanes of each token ----
    float ssx = ssx0 + ssx1;
    ssx += __shfl_xor(ssx, 16, 64);
    ssx += __shfl_xor(ssx, 32, 64);
    if (lane < 16) Cn[wv][lane] = ssx;
    // ---- expert norm partials: combine the 4 fq-lanes of each expert ----
    #pragma unroll
    for (int j = 0; j < 4; ++j) {
        wss[j] += __shfl_xor(wss[j], 16, 64);
        wss[j] += __shfl_xor(wss[j], 32, 64);
    }
    if (fq == 0) {
        #pragma unroll
        for (int j = 0; j < 4; ++j) Wn[wv][16 * j + n] = wss[j];
    }
    __syncthreads();

    // ---- epilogue: wave w finalizes tokens 2w, 2w+1 (lane = expert) ----
    #pragma unroll
    for (int tt = 0; tt < 2; ++tt) {
        const int t = wv * 2 + tt;
        float gsum = 0.f, csum = 0.f, wsum = 0.f;
        #pragma unroll
        for (int w = 0; w < NWAVE; ++w) {
            gsum += Sd[w][t * RS + lane];
            csum += Cn[w][t];
            wsum += Wn[w][lane];
        }
        const float S = fmaf(-2.f * INVSCALE, gsum, csum) + wsum;
        const float logit = -sqrtf(S);

        float v1 = logit; int i1 = lane;
        #pragma unroll
        for (int off = 32; off > 0; off >>= 1) {
            float ov = __shfl_xor(v1, off, 64);
            int   oi = __shfl_xor(i1, off, 64);
            if (ov > v1 || (ov == v1 && oi < i1)) { v1 = ov; i1 = oi; }
        }
        float v2 = (lane == i1) ? -__builtin_inff() : logit;
        int   i2 = lane;
        #pragma unroll
        for (int off = 32; off > 0; off >>= 1) {
            float ov = __shfl_xor(v2, off, 64);
            int   oi = __shfl_xor(i2, off, 64);
            if (ov > v2 || (ov == v2 && oi < i2)) { v2 = ov; i2 = oi; }
        }
        const float e2  = expf(v2 - v1);
        const float inv = 1.f / (1.f + e2);
        const float o = (lane == i1) ? inv : ((lane == i2) ? e2 * inv : 0.f);
        out[(size_t)(tok0 + t) * NEXP + lane] = o;
    }
}

// ---------------------------------------------------------------------------
extern "C" void kernel_launch(void* const* d_in, const int* in_sizes, int n_in,
                              void* d_out, int out_size, void* d_ws, size_t ws_size,
                              hipStream_t stream) {
    const float* t1 = (const float*)d_in[0];
    const float* t2 = (const float*)d_in[1];
    const float* W  = (const float*)d_in[2];
    float* out = (float*)d_out;
    (void)d_ws; (void)ws_size;   // workspace no longer needed: single fused kernel

    gate_all<<<NTOK / 16, 512, 0, stream>>>(t1, t2, W, out);
}

// Round 4
// 84.702 us; speedup vs baseline: 1.2683x; 1.2683x over previous
//
#include <hip/hip_runtime.h>
#include <math.h>

#define NTOK 4096
#define NDIM 1024
#define KTOT 2048
#define NEXP 64
#define TPB_TOK 32           // tokens per block (2 MFMA A-tiles) -> W amortized 2x
#define KBLK 1024            // K per block (2 blocks per token-tile split K)
#define NWAVE 8              // intra-block split-K waves
#define KCH  (KBLK / NWAVE)  // 128 k per wave
#define NSTEP (KCH / 32)     // 4 mfma K-steps per wave
#define RS   68              // LDS row stride (floats) for the reduce buffer
#define NTILE (NTOK / TPB_TOK)   // 128 token tiles

typedef _Float16 half8 __attribute__((ext_vector_type(8)));
typedef float    floatx4 __attribute__((ext_vector_type(4)));

#define XSCALE 16.0f
#define WSCALE 1024.0f
#define INVSCALE (1.0f / (16.0f * 1024.0f))

struct h2pair { _Float16 h, l; };
__device__ __forceinline__ h2pair split2(float v) {
    h2pair r;
    r.h = (_Float16)v;
    r.l = (_Float16)(v - (float)r.h);
    return r;
}

// ---------------------------------------------------------------------------
// prep_w: W (fp32) -> scaled fp16 hi/lo planes in FRAGMENT-MAJOR layout
//   WhT[((k>>3)*NEXP + e)*8 + (k&7)]  (256 B contiguous per B-fragment load)
// Also computes ||w_e||^2.  grid = 64 blocks x 256 threads.
// (Round-3 lesson: fusing this into the main kernel costs +21 us — the fp32
//  W re-read doubles cacheline touches and re-does conversion VALU 256x.)
// ---------------------------------------------------------------------------
__global__ __launch_bounds__(256) void prep_w(const float* __restrict__ W,
                                              _Float16* __restrict__ WhT,
                                              _Float16* __restrict__ WlT,
                                              float* __restrict__ nrm) {
    const int e = blockIdx.x, t = threadIdx.x;   // t = k-octet 0..255
    const float* row = W + (size_t)e * KTOT + t * 8;
    const float4 a = *reinterpret_cast<const float4*>(row);
    const float4 b = *reinterpret_cast<const float4*>(row + 4);
    float ss = fmaf(a.x, a.x, fmaf(a.y, a.y, fmaf(a.z, a.z, fmaf(a.w, a.w, 0.f))));
    ss = fmaf(b.x, b.x, fmaf(b.y, b.y, fmaf(b.z, b.z, fmaf(b.w, b.w, ss))));

    const h2pair p0 = split2(a.x * WSCALE), p1 = split2(a.y * WSCALE);
    const h2pair p2 = split2(a.z * WSCALE), p3 = split2(a.w * WSCALE);
    const h2pair p4 = split2(b.x * WSCALE), p5 = split2(b.y * WSCALE);
    const h2pair p6 = split2(b.z * WSCALE), p7 = split2(b.w * WSCALE);
    half8 h, l;
    h[0]=p0.h; h[1]=p1.h; h[2]=p2.h; h[3]=p3.h; h[4]=p4.h; h[5]=p5.h; h[6]=p6.h; h[7]=p7.h;
    l[0]=p0.l; l[1]=p1.l; l[2]=p2.l; l[3]=p3.l; l[4]=p4.l; l[5]=p5.l; l[6]=p6.l; l[7]=p7.l;
    const size_t idx = ((size_t)t * NEXP + e) * 8;
    *reinterpret_cast<half8*>(WhT + idx) = h;
    *reinterpret_cast<half8*>(WlT + idx) = l;

    #pragma unroll
    for (int off = 32; off > 0; off >>= 1) ss += __shfl_down(ss, off, 64);
    __shared__ float red[4];
    const int lane = t & 63, wv = t >> 6;
    if (lane == 0) red[wv] = ss;
    __syncthreads();
    if (t == 0) nrm[e] = (red[0] + red[1]) + (red[2] + red[3]);
}

// ---------------------------------------------------------------------------
// gate_main: 256 blocks = 128 token-tiles (32 tokens) x 2 K-halves.
// Theory: kernel is bound by per-CU vmem cacheline-access throughput
// (occupancy-invariant per rounds 0/2 A/B; nothing else saturated in round-3
// counters).  Loading each W B-fragment ONCE and feeding TWO 16-token A-tiles
// halves W line-touches per block (8192 -> 4096); X stays 4096; total 12288
// -> 8192 per block => predict ~1.5x faster main loop.
// Each wave handles k-chunk [kb*1024 + wv*128, +128) for 32 tokens.
// Partial dot-sums + ||x||^2 partials go to workspace; finalize combines.
// ---------------------------------------------------------------------------
__global__ __launch_bounds__(512) void gate_main(const float* __restrict__ t1,
                                                 const float* __restrict__ t2,
                                                 const _Float16* __restrict__ WhT,
                                                 const _Float16* __restrict__ WlT,
                                                 float* __restrict__ dotp,
                                                 float* __restrict__ xnp) {
    __shared__ float Sd[NWAVE][TPB_TOK * RS];  // per-wave 32x64 partial dots
    __shared__ float Cn[NWAVE][TPB_TOK];       // per-wave per-token ||x||^2 partials

    const int tid  = threadIdx.x;
    const int lane = tid & 63;
    const int wv   = tid >> 6;            // 0..7 = intra-block split-K chunk
    const int bid  = blockIdx.x;
    const int tile = bid >> 1;            // token tile 0..127
    const int kb   = bid & 1;             // K half 0..1
    const int tok0 = tile * TPB_TOK;
    const int kbase = kb * KBLK + wv * KCH;
    const int n  = lane & 15;             // fragment row (token / expert)
    const int fq = lane >> 4;             // k-octet selector

    // X: two A-tiles; KCH=128 divides NDIM so each chunk is in one tensor
    const float* __restrict__ xsrc = (kbase < NDIM) ? t1 : t2;
    const int koff = (kbase < NDIM) ? kbase : (kbase - NDIM);
    const float* __restrict__ xb0 = xsrc + (size_t)(tok0 + n) * NDIM + koff + fq * 8;
    const float* __restrict__ xb1 = xsrc + (size_t)(tok0 + 16 + n) * NDIM + koff + fq * 8;
    // W: fragment-major; k-octet index = kbase/8 + s*4 + fq, expert row 16j+n
    const _Float16* __restrict__ whb = WhT + ((size_t)(kbase >> 3) + fq) * (NEXP * 8) + n * 8;
    const _Float16* __restrict__ wlb = WlT + ((size_t)(kbase >> 3) + fq) * (NEXP * 8) + n * 8;

    floatx4 acc[2][4];
    #pragma unroll
    for (int tt = 0; tt < 2; ++tt)
        #pragma unroll
        for (int j = 0; j < 4; ++j) { acc[tt][j][0]=0.f; acc[tt][j][1]=0.f; acc[tt][j][2]=0.f; acc[tt][j][3]=0.f; }
    float ss0a = 0.f, ss0b = 0.f, ss1a = 0.f, ss1b = 0.f;

    #pragma unroll
    for (int s = 0; s < NSTEP; ++s) {
        const float4 x00 = *reinterpret_cast<const float4*>(xb0 + s * 32);
        const float4 x01 = *reinterpret_cast<const float4*>(xb0 + s * 32 + 4);
        const float4 x10 = *reinterpret_cast<const float4*>(xb1 + s * 32);
        const float4 x11 = *reinterpret_cast<const float4*>(xb1 + s * 32 + 4);
        half8 bh[4], bl[4];
        #pragma unroll
        for (int j = 0; j < 4; ++j) {
            bh[j] = *reinterpret_cast<const half8*>(whb + (size_t)s * 4 * (NEXP * 8) + j * 128);
            bl[j] = *reinterpret_cast<const half8*>(wlb + (size_t)s * 4 * (NEXP * 8) + j * 128);
        }
        ss0a = fmaf(x00.x, x00.x, fmaf(x00.y, x00.y, fmaf(x00.z, x00.z, fmaf(x00.w, x00.w, ss0a))));
        ss0b = fmaf(x01.x, x01.x, fmaf(x01.y, x01.y, fmaf(x01.z, x01.z, fmaf(x01.w, x01.w, ss0b))));
        ss1a = fmaf(x10.x, x10.x, fmaf(x10.y, x10.y, fmaf(x10.z, x10.z, fmaf(x10.w, x10.w, ss1a))));
        ss1b = fmaf(x11.x, x11.x, fmaf(x11.y, x11.y, fmaf(x11.z, x11.z, fmaf(x11.w, x11.w, ss1b))));
        const h2pair q0 = split2(x00.x * XSCALE), q1 = split2(x00.y * XSCALE);
        const h2pair q2 = split2(x00.z * XSCALE), q3 = split2(x00.w * XSCALE);
        const h2pair q4 = split2(x01.x * XSCALE), q5 = split2(x01.y * XSCALE);
        const h2pair q6 = split2(x01.z * XSCALE), q7 = split2(x01.w * XSCALE);
        const h2pair r0 = split2(x10.x * XSCALE), r1 = split2(x10.y * XSCALE);
        const h2pair r2 = split2(x10.z * XSCALE), r3 = split2(x10.w * XSCALE);
        const h2pair r4 = split2(x11.x * XSCALE), r5 = split2(x11.y * XSCALE);
        const h2pair r6 = split2(x11.z * XSCALE), r7 = split2(x11.w * XSCALE);
        half8 ah0, al0, ah1, al1;
        ah0[0]=q0.h; ah0[1]=q1.h; ah0[2]=q2.h; ah0[3]=q3.h; ah0[4]=q4.h; ah0[5]=q5.h; ah0[6]=q6.h; ah0[7]=q7.h;
        al0[0]=q0.l; al0[1]=q1.l; al0[2]=q2.l; al0[3]=q3.l; al0[4]=q4.l; al0[5]=q5.l; al0[6]=q6.l; al0[7]=q7.l;
        ah1[0]=r0.h; ah1[1]=r1.h; ah1[2]=r2.h; ah1[3]=r3.h; ah1[4]=r4.h; ah1[5]=r5.h; ah1[6]=r6.h; ah1[7]=r7.h;
        al1[0]=r0.l; al1[1]=r1.l; al1[2]=r2.l; al1[3]=r3.l; al1[4]=r4.l; al1[5]=r5.l; al1[6]=r6.l; al1[7]=r7.l;
        // Each B fragment feeds both A-tiles: W vmem amortized 2x.
        #pragma unroll
        for (int j = 0; j < 4; ++j) {
            acc[0][j] = __builtin_amdgcn_mfma_f32_16x16x32_f16(ah0, bh[j], acc[0][j], 0, 0, 0);
            acc[1][j] = __builtin_amdgcn_mfma_f32_16x16x32_f16(ah1, bh[j], acc[1][j], 0, 0, 0);
        }
        #pragma unroll
        for (int j = 0; j < 4; ++j) {
            acc[0][j] = __builtin_amdgcn_mfma_f32_16x16x32_f16(al0, bh[j], acc[0][j], 0, 0, 0);
            acc[1][j] = __builtin_amdgcn_mfma_f32_16x16x32_f16(al1, bh[j], acc[1][j], 0, 0, 0);
        }
        #pragma unroll
        for (int j = 0; j < 4; ++j) {
            acc[0][j] = __builtin_amdgcn_mfma_f32_16x16x32_f16(ah0, bl[j], acc[0][j], 0, 0, 0);
            acc[1][j] = __builtin_amdgcn_mfma_f32_16x16x32_f16(ah1, bl[j], acc[1][j], 0, 0, 0);
        }
    }

    // ---- deposit partial dots (C/D layout: token = tt*16 + fq*4+i, expert 16j+n)
    #pragma unroll
    for (int tt = 0; tt < 2; ++tt)
        #pragma unroll
        for (int j = 0; j < 4; ++j)
            #pragma unroll
            for (int i = 0; i < 4; ++i)
                Sd[wv][(tt * 16 + fq * 4 + i) * RS + 16 * j + n] = acc[tt][j][i];

    // ---- token norm partials: combine the 4 fq-lanes of each token ----
    float ss0 = ss0a + ss0b, ss1 = ss1a + ss1b;
    ss0 += __shfl_xor(ss0, 16, 64);
    ss0 += __shfl_xor(ss0, 32, 64);
    ss1 += __shfl_xor(ss1, 16, 64);
    ss1 += __shfl_xor(ss1, 32, 64);
    if (lane < 16) { Cn[wv][lane] = ss0; Cn[wv][16 + lane] = ss1; }
    __syncthreads();

    // ---- reduce over the 8 intra-block waves; write partials (wave w: 4 tokens)
    #pragma unroll
    for (int tt = 0; tt < 4; ++tt) {
        const int t = wv * 4 + tt;
        float gsum = 0.f, csum = 0.f;
        #pragma unroll
        for (int w = 0; w < NWAVE; ++w) {
            gsum += Sd[w][t * RS + lane];
            csum += Cn[w][t];
        }
        dotp[((size_t)(tile * 2 + kb) * TPB_TOK + t) * NEXP + lane] = gsum;
        if (lane == 0) xnp[(size_t)(tile * 2 + kb) * TPB_TOK + t] = csum;
    }
}

// ---------------------------------------------------------------------------
// finalize: one wave per token — combine the 2 K-half partials, then
// logit = -sqrt(||x||^2 - 2 x.w + ||w||^2), top-2, softmax, scatter.
// grid = 512 blocks x 512 threads (8 waves = 8 tokens per block).
// ---------------------------------------------------------------------------
__global__ __launch_bounds__(512) void finalize(const float* __restrict__ dotp,
                                                const float* __restrict__ xnp,
                                                const float* __restrict__ nrm,
                                                float* __restrict__ out) {
    const int tid  = threadIdx.x;
    const int lane = tid & 63;
    const int wv   = tid >> 6;
    const int tok  = blockIdx.x * 8 + wv;
    const int tile = tok >> 5;            // /TPB_TOK
    const int t    = tok & 31;

    const float g = dotp[((size_t)(tile * 2 + 0) * TPB_TOK + t) * NEXP + lane]
                  + dotp[((size_t)(tile * 2 + 1) * TPB_TOK + t) * NEXP + lane];
    const float c = xnp[(size_t)(tile * 2 + 0) * TPB_TOK + t]
                  + xnp[(size_t)(tile * 2 + 1) * TPB_TOK + t];
    const float S = fmaf(-2.f * INVSCALE, g, c) + nrm[lane];
    const float logit = -sqrtf(S);

    float v1 = logit; int i1 = lane;
    #pragma unroll
    for (int off = 32; off > 0; off >>= 1) {
        float ov = __shfl_xor(v1, off, 64);
        int   oi = __shfl_xor(i1, off, 64);
        if (ov > v1 || (ov == v1 && oi < i1)) { v1 = ov; i1 = oi; }
    }
    float v2 = (lane == i1) ? -__builtin_inff() : logit;
    int   i2 = lane;
    #pragma unroll
    for (int off = 32; off > 0; off >>= 1) {
        float ov = __shfl_xor(v2, off, 64);
        int   oi = __shfl_xor(i2, off, 64);
        if (ov > v2 || (ov == v2 && oi < i2)) { v2 = ov; i2 = oi; }
    }
    const float e2  = expf(v2 - v1);
    const float inv = 1.f / (1.f + e2);
    const float o = (lane == i1) ? inv : ((lane == i2) ? e2 * inv : 0.f);
    out[(size_t)tok * NEXP + lane] = o;
}

// ---------------------------------------------------------------------------
extern "C" void kernel_launch(void* const* d_in, const int* in_sizes, int n_in,
                              void* d_out, int out_size, void* d_ws, size_t ws_size,
                              hipStream_t stream) {
    const float* t1 = (const float*)d_in[0];
    const float* t2 = (const float*)d_in[1];
    const float* W  = (const float*)d_in[2];
    float* out = (float*)d_out;

    char* ws = (char*)d_ws;
    float*    nrm  = (float*)ws;                        // 64 floats
    _Float16* WhT  = (_Float16*)(nrm + NEXP);           // 131072 halves (256 KB)
    _Float16* WlT  = WhT + (size_t)NEXP * KTOT;         // 256 KB
    float*    dotp = (float*)(WlT + (size_t)NEXP * KTOT);   // 256*32*64 floats (2 MB)
    float*    xnp  = dotp + (size_t)NTILE * 2 * TPB_TOK * NEXP; // 8192 floats

    prep_w<<<NEXP, 256, 0, stream>>>(W, WhT, WlT, nrm);
    gate_main<<<NTILE * 2, 512, 0, stream>>>(t1, t2, WhT, WlT, dotp, xnp);
    finalize<<<NTOK / 8, 512, 0, stream>>>(dotp, xnp, nrm, out);
}